// Round 1
// baseline (1394.556 us; speedup 1.0000x reference)
//
#include <hip/hip_runtime.h>
#include <hip/hip_fp16.h>

typedef _Float16 half8 __attribute__((ext_vector_type(8)));
typedef _Float16 half4 __attribute__((ext_vector_type(4)));
typedef float floatx4 __attribute__((ext_vector_type(4)));

#define BB 4096
#define SS 50
#define HH 256
// LDS row stride in halfs: 256+8 -> 528 bytes, 16B aligned, odd multiple of 16B
#define APAD 264

// ---- phase 0: convert W_ih / W_hh fp32 -> fp16 into workspace ----
__global__ void cvt_w(const float* __restrict__ wih,
                      const float* __restrict__ whh,
                      _Float16* __restrict__ ws) {
    int idx = (blockIdx.x * 256 + threadIdx.x) * 4;   // 4 floats per thread
    const int half1 = 768 * 256;                      // 196608
    const float* src = (idx < half1) ? (wih + idx) : (whh + (idx - half1));
    float4 v = *(const float4*)src;
    half4 h;
    h[0] = (_Float16)v.x; h[1] = (_Float16)v.y;
    h[2] = (_Float16)v.z; h[3] = (_Float16)v.w;
    *(half4*)(ws + idx) = h;
}

// ---- fused GRU scan: one block = 16 batch rows, all 50 steps ----
__global__ __launch_bounds__(512, 2) void gru_scan(
    const float* __restrict__ C, const float* __restrict__ G,
    const _Float16* __restrict__ Wih, const _Float16* __restrict__ Whh,
    const float* __restrict__ bih, const float* __restrict__ bhh,
    float* __restrict__ out)
{
    __shared__ _Float16 cA[16 * APAD];       // C_s tile, A-ready row-major f16
    __shared__ _Float16 hA[2][16 * APAD];    // h tile, double-buffered
    __shared__ float gS[16];

    const int tid  = threadIdx.x;
    const int wave = tid >> 6;               // 0..7, owns h-cols [32w,32w+32)
    const int lane = tid & 63;
    const int q    = lane >> 4;              // quad 0..3
    const int c    = lane & 15;              // A: row m; B: col n; D: col n
    const int rb   = blockIdx.x * 16;

    // biases: gate g in {r,z,n}, sub-tile t in {0,1}; col = g*256 + wave*32 + t*16 + c
    float bi[3][2], bh[3][2];
#pragma unroll
    for (int g = 0; g < 3; ++g)
#pragma unroll
        for (int t = 0; t < 2; ++t) {
            int n = g * 256 + wave * 32 + t * 16 + c;
            bi[g][t] = bih[n];
            bh[g][t] = bhh[n];
        }

    // per-lane weight fragment base pointers (stationary across steps)
    const _Float16* wiP[3][2];
    const _Float16* whP[3][2];
#pragma unroll
    for (int g = 0; g < 3; ++g)
#pragma unroll
        for (int t = 0; t < 2; ++t) {
            int n0 = g * 256 + wave * 32 + t * 16;
            wiP[g][t] = Wih + (size_t)(n0 + c) * HH + q * 8;
            whP[g][t] = Whh + (size_t)(n0 + c) * HH + q * 8;
        }

    // persistent h, fp32, D-layout: h[m=q*4+r][col=wave*32+t*16+c]
    float hreg[2][4];
#pragma unroll
    for (int t = 0; t < 2; ++t)
#pragma unroll
        for (int r = 0; r < 4; ++r) hreg[t][r] = 0.f;

    for (int i = tid; i < 16 * APAD; i += 512) hA[0][i] = (_Float16)0.f;
    __syncthreads();

    // staging mapping: 512 threads cover 16 rows x 32 chunks of 8 floats
    const int m_st = tid & 15;
    const int ch   = tid >> 4;               // 0..31
    const float* crow = C + (size_t)(rb + m_st) * (SS * HH) + ch * 8;

    for (int s = 0; s < SS; ++s) {
        // ---- stage C[:, s, :] -> cA (f16), and G[:, s] -> gS ----
        {
            const float4* p = (const float4*)(crow + (size_t)s * HH);
            float4 v0 = p[0];
            float4 v1 = p[1];
            half8 hv;
            hv[0] = (_Float16)v0.x; hv[1] = (_Float16)v0.y;
            hv[2] = (_Float16)v0.z; hv[3] = (_Float16)v0.w;
            hv[4] = (_Float16)v1.x; hv[5] = (_Float16)v1.y;
            hv[6] = (_Float16)v1.z; hv[7] = (_Float16)v1.w;
            *(half8*)&cA[m_st * APAD + ch * 8] = hv;
            if (tid < 16) gS[tid] = G[(size_t)(rb + tid) * SS + s];
        }
        __syncthreads();

        const _Float16* hAr = hA[s & 1];

        floatx4 acc_i[3][2], acc_h[3][2];
#pragma unroll
        for (int g = 0; g < 3; ++g)
#pragma unroll
            for (int t = 0; t < 2; ++t) {
                acc_i[g][t] = (floatx4){0.f, 0.f, 0.f, 0.f};
                acc_h[g][t] = (floatx4){0.f, 0.f, 0.f, 0.f};
            }

        // ---- K loop: 8 kt x (6 n-tiles) x (gi,gh) MFMAs ----
#pragma unroll
        for (int kt = 0; kt < 8; ++kt) {
            half8 aC = *(const half8*)&cA[c * APAD + kt * 32 + q * 8];
            half8 aH = *(const half8*)&hAr[c * APAD + kt * 32 + q * 8];
#pragma unroll
            for (int g = 0; g < 3; ++g)
#pragma unroll
                for (int t = 0; t < 2; ++t) {
                    half8 bI = *(const half8*)(wiP[g][t] + kt * 32);
                    half8 bH = *(const half8*)(whP[g][t] + kt * 32);
                    acc_i[g][t] = __builtin_amdgcn_mfma_f32_16x16x32_f16(aC, bI, acc_i[g][t], 0, 0, 0);
                    acc_h[g][t] = __builtin_amdgcn_mfma_f32_16x16x32_f16(aH, bH, acc_h[g][t], 0, 0, 0);
                }
        }

        // ---- gates + h update (fp32), write next hA buffer ----
        _Float16* hAw = hA[(s + 1) & 1];
#pragma unroll
        for (int t = 0; t < 2; ++t)
#pragma unroll
            for (int r = 0; r < 4; ++r) {
                int m = q * 4 + r;
                float ir  = acc_i[0][t][r] + bi[0][t];
                float hr  = acc_h[0][t][r] + bh[0][t];
                float iz  = acc_i[1][t][r] + bi[1][t];
                float hz  = acc_h[1][t][r] + bh[1][t];
                float in_ = acc_i[2][t][r] + bi[2][t];
                float hn  = acc_h[2][t][r] + bh[2][t];
                float rg  = 1.f / (1.f + __expf(-(ir + hr)));
                float zg  = 1.f / (1.f + __expf(-(iz + hz)));
                float pre = in_ + rg * hn;
                float ap  = fabsf(pre);
                float e2  = __expf(-2.f * ap);
                float th  = (1.f - e2) / (1.f + e2);
                float ng  = (pre < 0.f) ? -th : th;
                float hold = hreg[t][r];
                float hnew = (1.f - zg) * ng + zg * hold;
                float gg   = gS[m];
                float hout = gg * hnew + (1.f - gg) * hold;
                hreg[t][r] = hout;
                hAw[m * APAD + wave * 32 + t * 16 + c] = (_Float16)hout;
            }
        __syncthreads();
    }

    // ---- write h_final (fp32) ----
#pragma unroll
    for (int t = 0; t < 2; ++t)
#pragma unroll
        for (int r = 0; r < 4; ++r) {
            int m = q * 4 + r;
            out[(size_t)(rb + m) * HH + wave * 32 + t * 16 + c] = hreg[t][r];
        }
}

extern "C" void kernel_launch(void* const* d_in, const int* in_sizes, int n_in,
                              void* d_out, int out_size, void* d_ws, size_t ws_size,
                              hipStream_t stream) {
    const float* C   = (const float*)d_in[0];
    const float* G   = (const float*)d_in[1];
    const float* Wih = (const float*)d_in[2];
    const float* Whh = (const float*)d_in[3];
    const float* bih = (const float*)d_in[4];
    const float* bhh = (const float*)d_in[5];
    _Float16* wsh = (_Float16*)d_ws;   // [0,196608): W_ih f16; [196608,393216): W_hh f16

    cvt_w<<<384, 256, 0, stream>>>(Wih, Whh, wsh);
    gru_scan<<<BB / 16, 512, 0, stream>>>(C, G, wsh, wsh + 768 * 256,
                                          bih, bhh, (float*)d_out);
}